// Round 4
// baseline (42.414 us; speedup 1.0000x reference)
//
#include <hip/hip_runtime.h>
#include <stdint.h>

#define DIM_IN  4096
#define DIM_OUT 4096
#define BATCH   64
// words along dim_in: 4096/64 = 64

typedef unsigned long long u64;
typedef uint32_t u32;

// ---------------------------------------------------------------------------
// Input-format detection (first 8 u32 words):
//   int32 0/1 or float 0.0/1.0 -> "word" layout (4B per bool)
//   uint8 0/1                  -> "byte" layout (1B per bool)
// A byte-layout word is in {0,1} only if its top 3 bytes are all 0
// (P ~ 2^-24 per word for random bits); over 8 words P ~ 2^-192.
// Round-3 FETCH_SIZE (33.4 MB > byte-ideal 16.7 MB) says inputs are words.
// ---------------------------------------------------------------------------
__device__ __forceinline__ bool is_word_fmt(const u32* __restrict__ p) {
    bool words = true;
#pragma unroll
    for (int i = 0; i < 8; ++i) {
        u32 v = p[i];
        if (v > 1u && v != 0x3F800000u) words = false;
    }
    return words;
}

// ---------------------------------------------------------------------------
// K1 (fused pack), 1040 blocks x 256 threads:
//  blocks 0..1023  : mask pack. One wave per (w, 64-col tile); lane = column.
//                    Lane builds u64 of rows w*64..w*64+63 for its column via
//                    64 u32 loads (per row the wave reads 256B coalesced).
//                    4 batches x 16 independent loads for MLP; ~30 VGPR.
//  blocks 1024..1039: x pack via wave ballot (64 waves x 64 words).
// ---------------------------------------------------------------------------
__global__ __launch_bounds__(256) void pack_kernel(
        const void* __restrict__ masks, const void* __restrict__ x,
        u64* __restrict__ mp, u64* __restrict__ xp) {
    const int bid = blockIdx.x;
    if (bid < 1024) {
        const bool words = is_word_fmt((const u32*)masks);
        const int wid = bid * 4 + (threadIdx.x >> 6);           // 0..4095
        const int w   = wid >> 6;                               // 0..63
        const int o   = ((wid & 63) << 6) + (threadIdx.x & 63); // 0..4095
        const int row0 = w * 64;

        u64 bits = 0;
        if (words) {
            const u32* pw = (const u32*)masks + (size_t)row0 * DIM_OUT + o;
#pragma unroll
            for (int rb = 0; rb < 4; ++rb) {
                u32 v[16];
#pragma unroll
                for (int r = 0; r < 16; ++r)
                    v[r] = pw[(size_t)(rb * 16 + r) * DIM_OUT];
#pragma unroll
                for (int r = 0; r < 16; ++r)
                    bits |= (u64)(v[r] != 0u) << (rb * 16 + r);
            }
        } else {
            const uint8_t* pb = (const uint8_t*)masks + (size_t)row0 * DIM_OUT + o;
#pragma unroll
            for (int rb = 0; rb < 4; ++rb) {
                uint8_t v[16];
#pragma unroll
                for (int r = 0; r < 16; ++r)
                    v[r] = pb[(size_t)(rb * 16 + r) * DIM_OUT];
#pragma unroll
                for (int r = 0; r < 16; ++r)
                    bits |= (u64)(v[r] != 0u) << (rb * 16 + r);
            }
        }
        mp[(size_t)w * DIM_OUT + o] = bits;
    } else {
        // ------------------- x pack -------------------
        const bool words = is_word_fmt((const u32*)x);
        const int bxid = bid - 1024;                          // 0..15
        const int wave = bxid * 4 + (threadIdx.x >> 6);       // 0..63
        const int lane = threadIdx.x & 63;
        const int base = wave * 64;                           // word index base

#pragma unroll 16
        for (int k = 0; k < 64; ++k) {
            const int idx = base + k;                         // 0..4095
            const size_t e = (size_t)idx * 64 + lane;         // element index
            bool pred;
            if (words) pred = ((const u32*)x)[e] != 0u;
            else       pred = ((const uint8_t*)x)[e] != 0u;
            const u64 m = __ballot(pred);
            if (lane == 0) xp[idx] = m;
        }
    }
}

// ---------------------------------------------------------------------------
// K2: out[b][o] = ((4096 - sum_w popc(xp[b][w] ^ mp[w][o])) > thr[o]) ? 1 : 0
// Output dtype INT32 (bool output -> int32 harness path).
// Grid: (16 o-blocks, 16 b-blocks) x 256 threads; 4 batch rows per thread.
// mp loads coalesced (consecutive o per lane); xp block-uniform -> scalar.
// ---------------------------------------------------------------------------
__global__ __launch_bounds__(256) void bnn_kernel(
        const u64* __restrict__ mp, const u64* __restrict__ xp,
        const int* __restrict__ thr, int* __restrict__ out) {
    const int o  = blockIdx.x * 256 + threadIdx.x;
    const int b0 = blockIdx.y * 4;

    const u64* __restrict__ x0 = xp + (size_t)(b0 + 0) * 64;
    const u64* __restrict__ x1 = xp + (size_t)(b0 + 1) * 64;
    const u64* __restrict__ x2 = xp + (size_t)(b0 + 2) * 64;
    const u64* __restrict__ x3 = xp + (size_t)(b0 + 3) * 64;

    int a0 = 0, a1 = 0, a2 = 0, a3 = 0;
#pragma unroll 16
    for (int w = 0; w < 64; ++w) {
        const u64 mw = mp[(size_t)w * DIM_OUT + o];
        a0 += __popcll(x0[w] ^ mw);
        a1 += __popcll(x1[w] ^ mw);
        a2 += __popcll(x2[w] ^ mw);
        a3 += __popcll(x3[w] ^ mw);
    }

    const int t = thr[o];
    out[(size_t)(b0 + 0) * DIM_OUT + o] = (DIM_IN - a0) > t ? 1 : 0;
    out[(size_t)(b0 + 1) * DIM_OUT + o] = (DIM_IN - a1) > t ? 1 : 0;
    out[(size_t)(b0 + 2) * DIM_OUT + o] = (DIM_IN - a2) > t ? 1 : 0;
    out[(size_t)(b0 + 3) * DIM_OUT + o] = (DIM_IN - a3) > t ? 1 : 0;
}

// ---------------------------------------------------------------------------
extern "C" void kernel_launch(void* const* d_in, const int* in_sizes, int n_in,
                              void* d_out, int out_size, void* d_ws, size_t ws_size,
                              hipStream_t stream) {
    const void* x     = d_in[0];                 // bool [64][4096]
    const void* masks = d_in[1];                 // bool [4096][4096]
    const int*  thr   = (const int*)d_in[2];     // int32 [4096]
    int* out = (int*)d_out;                      // [64][4096] int32 0/1

    u64* mp = (u64*)d_ws;                                        // 2 MiB
    u64* xp = (u64*)((char*)d_ws + (size_t)64 * DIM_OUT * 8);    // 32 KiB

    pack_kernel<<<dim3(1040), dim3(256), 0, stream>>>(masks, x, mp, xp);
    bnn_kernel<<<dim3(16, 16), dim3(256), 0, stream>>>(mp, xp, thr, out);
}